// Round 3
// baseline (2138.644 us; speedup 1.0000x reference)
//
#include <hip/hip_runtime.h>
#include <hip/hip_bf16.h>
#include <math.h>

#define T_ 16
#define B_ 16
#define N_ 256
#define H_ 512
#define L_ 64
#define K_ 8
#define SCALE 0.04419417382415922f   // THETA / sqrt(512)

// ---- DPP helper ----
template <int CTRL>
__device__ __forceinline__ float dpp_mov(float x) {
  return __int_as_float(
      __builtin_amdgcn_update_dpp(0, __float_as_int(x), CTRL, 0xF, 0xF, false));
}

// 16-lane (DPP-row) inclusive sum; lane 15 of each 16-lane row holds the total.
__device__ __forceinline__ float reduce16(float v) {
  v += dpp_mov<0x111>(v);  // row_shr:1
  v += dpp_mov<0x112>(v);  // row_shr:2
  v += dpp_mov<0x114>(v);  // row_shr:4
  v += dpp_mov<0x118>(v);  // row_shr:8
  return v;
}

// ============================================================================
// Kernel 1: one WAVE per (b,n) tile; 4 waves/block share one b (and its 32KB
// q LDS stage).  Lane split: r = lane>>4 picks one of 4 key rows per group,
// c = lane&15 covers a 64-float h-chunk (float4 per lane).
//   - k loads: 4 x 256B segments per inst, every 64B line fully used
//   - per-dot reduction: 4 DPP steps amortized over 4 rows = 1 DPP/dot
//   - q via broadcast ds_read_b128 (2-way bank alias = free)
// ============================================================================
__global__ __launch_bounds__(256, 4) void score_kernel(
    const float* __restrict__ q, const float* __restrict__ keys,
    float* __restrict__ scores) {
  __shared__ float qs[8192];  // [chunk][t][c] float4 = 32 KB, q for this b

  const int bid  = blockIdx.x;   // 0..1023
  const int b    = bid >> 6;
  const int wave = threadIdx.x >> 6;
  const int lane = threadIdx.x & 63;
  const int n    = ((bid & 63) << 2) | wave;

  // ---- stage q[b]: qs[((ch*16 + t)*16 + c)] (float4 units) ----
  {
    const int tid = threadIdx.x;
#pragma unroll
    for (int k = 0; k < 8; ++k) {
      const int flat = tid + (k << 8);       // float4 index, 0..2047
      const int c  = flat & 15;
      const int t  = (flat >> 4) & 15;
      const int ch = flat >> 8;
      const float4 v =
          *(const float4*)(q + ((size_t)t * B_ + b) * H_ + ch * 64 + c * 4);
      *(float4*)(qs + (size_t)flat * 4) = v;
    }
  }
  __syncthreads();

  const int r = lane >> 4;
  const int c = lane & 15;
  const float* __restrict__ kb =
      keys + ((size_t)n * B_ + b) * (size_t)(L_ * H_);

  float smax[T_];
#pragma unroll
  for (int t = 0; t < T_; ++t) smax[t] = -3.4e38f;

  for (int gp = 0; gp < 8; ++gp) {  // rows jA = 8gp + r, jB = 8gp + 4 + r
    const float* pA = kb + (size_t)(8 * gp + r) * H_ + c * 4;
    const float* pB = pA + 4 * H_;

    float accA[T_], accB[T_];
#pragma unroll
    for (int t = 0; t < T_; ++t) accA[t] = accB[t] = 0.0f;

    float4 ka = *(const float4*)(pA);
    float4 kb4 = *(const float4*)(pB);

    for (int ch = 0; ch < 8; ++ch) {
      const int pf = (ch < 7 ? ch + 1 : 7) * 64;  // depth-1 prefetch (clamped)
      const float4 na = *(const float4*)(pA + pf);
      const float4 nb = *(const float4*)(pB + pf);

      const float* qv = qs + ((size_t)(ch << 8) << 2);  // qs[ch][0][0]
#pragma unroll
      for (int t = 0; t < T_; ++t) {
        const float4 q4 = *(const float4*)(qv + (((t << 4) + c) << 2));
        accA[t] = fmaf(ka.x, q4.x, accA[t]);
        accA[t] = fmaf(ka.y, q4.y, accA[t]);
        accA[t] = fmaf(ka.z, q4.z, accA[t]);
        accA[t] = fmaf(ka.w, q4.w, accA[t]);
        accB[t] = fmaf(kb4.x, q4.x, accB[t]);
        accB[t] = fmaf(kb4.y, q4.y, accB[t]);
        accB[t] = fmaf(kb4.z, q4.z, accB[t]);
        accB[t] = fmaf(kb4.w, q4.w, accB[t]);
      }
      ka = na;
      kb4 = nb;
    }

    // 16-lane reduce (4 rows in parallel); results valid at c == 15
#pragma unroll
    for (int t = 0; t < T_; ++t) {
      const float sA = reduce16(accA[t]);
      const float sB = reduce16(accB[t]);
      smax[t] = fmaxf(smax[t], fmaxf(sA, sB));
    }
  }

  // combine the 4 row-groups (lanes 15/31/47/63 hold per-group maxima)
#pragma unroll
  for (int t = 0; t < T_; ++t) {
    float v = smax[t];
    v = fmaxf(v, __shfl_xor(v, 16));
    v = fmaxf(v, __shfl_xor(v, 32));
    if (lane == 15)
      scores[(size_t)t * (B_ * N_) + b * N_ + n] = v;  // raw score, (T,B,N)
  }
}

// ============================================================================
// Kernel 2: one wave per (t,b) row.  In-place softmax over N=256, then top-8
// (value desc, index asc on ties).  Indices written as float values.
// ============================================================================
__global__ __launch_bounds__(256) void softmax_topk_kernel(
    float* __restrict__ att, float* __restrict__ out_idx) {
  const int row  = blockIdx.x * 4 + (threadIdx.x >> 6);  // t*B + b
  const int lane = threadIdx.x & 63;

  float* s = att + (size_t)row * N_;
  const float4 v4 = *(const float4*)(s + 4 * lane);
  const float v[4] = {v4.x, v4.y, v4.z, v4.w};

  float m = fmaxf(fmaxf(v[0], v[1]), fmaxf(v[2], v[3]));
#pragma unroll
  for (int d = 1; d < 64; d <<= 1) m = fmaxf(m, __shfl_xor(m, d));

  float p[4];
#pragma unroll
  for (int e = 0; e < 4; ++e) p[e] = expf(SCALE * (v[e] - m));

  float sum = p[0] + p[1] + p[2] + p[3];
#pragma unroll
  for (int d = 1; d < 64; d <<= 1) sum += __shfl_xor(sum, d);
  const float inv = 1.0f / sum;

  float a[4];
#pragma unroll
  for (int e = 0; e < 4; ++e) a[e] = p[e] * inv;

  *(float4*)(s + 4 * lane) = make_float4(a[0], a[1], a[2], a[3]);

  float w[4] = {a[0], a[1], a[2], a[3]};
  for (int kk = 0; kk < K_; ++kk) {
    float bv = w[0];
    int bn = 4 * lane;
#pragma unroll
    for (int e = 1; e < 4; ++e) {
      if (w[e] > bv) { bv = w[e]; bn = 4 * lane + e; }
    }
#pragma unroll
    for (int d = 1; d < 64; d <<= 1) {
      const float ov = __shfl_xor(bv, d);
      const int on = __shfl_xor(bn, d);
      if (ov > bv || (ov == bv && on < bn)) { bv = ov; bn = on; }
    }
    if (lane == 0) out_idx[kk * (T_ * B_) + row] = (float)bn;  // (k,T,B)
#pragma unroll
    for (int e = 0; e < 4; ++e)
      if (4 * lane + e == bn) w[e] = -1.0f;
  }
}

extern "C" void kernel_launch(void* const* d_in, const int* in_sizes, int n_in,
                              void* d_out, int out_size, void* d_ws,
                              size_t ws_size, hipStream_t stream) {
  const float* q    = (const float*)d_in[0];   // (T,1,B,H) fp32
  const float* keys = (const float*)d_in[1];   // (N,B,L*H) fp32
  float* out = (float*)d_out;
  float* att = out;                 // 65536 floats: raw scores -> attention
  float* idx = out + T_ * B_ * N_;  // 2048 floats: (k,T,B) indices as floats

  score_kernel<<<B_ * (N_ / 4), 256, 0, stream>>>(q, keys, att);
  softmax_topk_kernel<<<(T_ * B_) / 4, 256, 0, stream>>>(att, idx);
}

// Round 4
// 1543.871 us; speedup vs baseline: 1.3852x; 1.3852x over previous
//
#include <hip/hip_runtime.h>
#include <hip/hip_bf16.h>
#include <math.h>

#define T_ 16
#define B_ 16
#define N_ 256
#define H_ 512
#define L_ 64
#define K_ 8
#define SCALE 0.04419417382415922f   // THETA / sqrt(512)

// ---- DPP helper ----
template <int CTRL>
__device__ __forceinline__ float dpp_mov(float x) {
  return __int_as_float(
      __builtin_amdgcn_update_dpp(0, __float_as_int(x), CTRL, 0xF, 0xF, false));
}

// 16-lane (DPP-row) inclusive sum; lane 15 of each 16-lane row holds the total.
__device__ __forceinline__ float reduce16(float v) {
  v += dpp_mov<0x111>(v);  // row_shr:1
  v += dpp_mov<0x112>(v);  // row_shr:2
  v += dpp_mov<0x114>(v);  // row_shr:4
  v += dpp_mov<0x118>(v);  // row_shr:8
  return v;
}

// ============================================================================
// Kernel 1: one WAVE per (b,n) tile; 4 waves/block share one b (and its 32KB
// q LDS stage).  Lane split: r = lane>>4 picks one of 4 key rows per group,
// c = lane&15 covers a 64-float h-chunk (float4 per lane).
//   - k loads: 4 x 256B segments per inst, every 64B line fully used
//   - per-dot reduction: 4 DPP steps amortized over 4 rows x 2 = 1/2 DPP/dot
//   - q via 4-way-broadcast ds_read_b128 (2-way bank alias = free)
// NOTE: no min-occupancy arg in __launch_bounds__ — (256,4) capped the
// allocator at 64 VGPRs and spilled the 48-float accumulator state to
// scratch (R2: 4.2GB FETCH, 2.1ms).  Natural allocation needs ~90-110.
// ============================================================================
__global__ __launch_bounds__(256) void score_kernel(
    const float* __restrict__ q, const float* __restrict__ keys,
    float* __restrict__ scores) {
  __shared__ float qs[8192];  // [chunk][t][c] float4 = 32 KB, q for this b

  const int bid  = blockIdx.x;   // 0..1023
  const int b    = bid >> 6;
  const int wave = threadIdx.x >> 6;
  const int lane = threadIdx.x & 63;
  const int n    = ((bid & 63) << 2) | wave;

  // ---- stage q[b]: qs[((ch*16 + t)*16 + c)] (float4 units) ----
  {
    const int tid = threadIdx.x;
#pragma unroll
    for (int k = 0; k < 8; ++k) {
      const int flat = tid + (k << 8);       // float4 index, 0..2047
      const int c  = flat & 15;
      const int t  = (flat >> 4) & 15;
      const int ch = flat >> 8;
      const float4 v =
          *(const float4*)(q + ((size_t)t * B_ + b) * H_ + ch * 64 + c * 4);
      *(float4*)(qs + (size_t)flat * 4) = v;
    }
  }
  __syncthreads();

  const int r = lane >> 4;
  const int c = lane & 15;
  const float* __restrict__ kb =
      keys + ((size_t)n * B_ + b) * (size_t)(L_ * H_);

  float smax[T_];
#pragma unroll
  for (int t = 0; t < T_; ++t) smax[t] = -3.4e38f;

  for (int gp = 0; gp < 8; ++gp) {  // rows jA = 8gp + r, jB = 8gp + 4 + r
    const float* pA = kb + (size_t)(8 * gp + r) * H_ + c * 4;
    const float* pB = pA + 4 * H_;

    float accA[T_], accB[T_];
#pragma unroll
    for (int t = 0; t < T_; ++t) accA[t] = accB[t] = 0.0f;

    float4 ka = *(const float4*)(pA);
    float4 kb4 = *(const float4*)(pB);

    for (int ch = 0; ch < 8; ++ch) {
      const int pf = (ch < 7 ? ch + 1 : 7) * 64;  // depth-1 prefetch (clamped)
      const float4 na = *(const float4*)(pA + pf);
      const float4 nb = *(const float4*)(pB + pf);

      const float* qv = qs + ((size_t)(ch << 8) << 2);  // qs[ch][0][0]
#pragma unroll
      for (int t = 0; t < T_; ++t) {
        const float4 q4 = *(const float4*)(qv + (((t << 4) + c) << 2));
        accA[t] = fmaf(ka.x, q4.x, accA[t]);
        accA[t] = fmaf(ka.y, q4.y, accA[t]);
        accA[t] = fmaf(ka.z, q4.z, accA[t]);
        accA[t] = fmaf(ka.w, q4.w, accA[t]);
        accB[t] = fmaf(kb4.x, q4.x, accB[t]);
        accB[t] = fmaf(kb4.y, q4.y, accB[t]);
        accB[t] = fmaf(kb4.z, q4.z, accB[t]);
        accB[t] = fmaf(kb4.w, q4.w, accB[t]);
      }
      ka = na;
      kb4 = nb;
    }

    // 16-lane reduce (4 row-groups in parallel); results valid at c == 15
#pragma unroll
    for (int t = 0; t < T_; ++t) {
      const float sA = reduce16(accA[t]);
      const float sB = reduce16(accB[t]);
      smax[t] = fmaxf(smax[t], fmaxf(sA, sB));
    }
  }

  // combine the 4 row-groups (lanes 15/31/47/63 hold per-group maxima)
#pragma unroll
  for (int t = 0; t < T_; ++t) {
    float v = smax[t];
    v = fmaxf(v, __shfl_xor(v, 16));
    v = fmaxf(v, __shfl_xor(v, 32));
    if (lane == 15)
      scores[(size_t)t * (B_ * N_) + b * N_ + n] = v;  // raw score, (T,B,N)
  }
}

// ============================================================================
// Kernel 2: one wave per (t,b) row.  In-place softmax over N=256, then top-8
// (value desc, index asc on ties).  Indices written as float values.
// ============================================================================
__global__ __launch_bounds__(256) void softmax_topk_kernel(
    float* __restrict__ att, float* __restrict__ out_idx) {
  const int row  = blockIdx.x * 4 + (threadIdx.x >> 6);  // t*B + b
  const int lane = threadIdx.x & 63;

  float* s = att + (size_t)row * N_;
  const float4 v4 = *(const float4*)(s + 4 * lane);
  const float v[4] = {v4.x, v4.y, v4.z, v4.w};

  float m = fmaxf(fmaxf(v[0], v[1]), fmaxf(v[2], v[3]));
#pragma unroll
  for (int d = 1; d < 64; d <<= 1) m = fmaxf(m, __shfl_xor(m, d));

  float p[4];
#pragma unroll
  for (int e = 0; e < 4; ++e) p[e] = expf(SCALE * (v[e] - m));

  float sum = p[0] + p[1] + p[2] + p[3];
#pragma unroll
  for (int d = 1; d < 64; d <<= 1) sum += __shfl_xor(sum, d);
  const float inv = 1.0f / sum;

  float a[4];
#pragma unroll
  for (int e = 0; e < 4; ++e) a[e] = p[e] * inv;

  *(float4*)(s + 4 * lane) = make_float4(a[0], a[1], a[2], a[3]);

  float w[4] = {a[0], a[1], a[2], a[3]};
  for (int kk = 0; kk < K_; ++kk) {
    float bv = w[0];
    int bn = 4 * lane;
#pragma unroll
    for (int e = 1; e < 4; ++e) {
      if (w[e] > bv) { bv = w[e]; bn = 4 * lane + e; }
    }
#pragma unroll
    for (int d = 1; d < 64; d <<= 1) {
      const float ov = __shfl_xor(bv, d);
      const int on = __shfl_xor(bn, d);
      if (ov > bv || (ov == bv && on < bn)) { bv = ov; bn = on; }
    }
    if (lane == 0) out_idx[kk * (T_ * B_) + row] = (float)bn;  // (k,T,B)
#pragma unroll
    for (int e = 0; e < 4; ++e)
      if (4 * lane + e == bn) w[e] = -1.0f;
  }
}

extern "C" void kernel_launch(void* const* d_in, const int* in_sizes, int n_in,
                              void* d_out, int out_size, void* d_ws,
                              size_t ws_size, hipStream_t stream) {
  const float* q    = (const float*)d_in[0];   // (T,1,B,H) fp32
  const float* keys = (const float*)d_in[1];   // (N,B,L*H) fp32
  float* out = (float*)d_out;
  float* att = out;                 // 65536 floats: raw scores -> attention
  float* idx = out + T_ * B_ * N_;  // 2048 floats: (k,T,B) indices as floats

  score_kernel<<<B_ * (N_ / 4), 256, 0, stream>>>(q, keys, att);
  softmax_topk_kernel<<<(T_ * B_) / 4, 256, 0, stream>>>(att, idx);
}

// Round 5
// 118.549 us; speedup vs baseline: 18.0402x; 13.0231x over previous
//
#include <hip/hip_runtime.h>
#include <hip/hip_bf16.h>
#include <math.h>

#define T_ 16
#define B_ 16
#define N_ 256
#define H_ 512
#define L_ 64
#define K_ 8
#define SCALE 0.04419417382415922f   // THETA / sqrt(512)

// ---- DPP helper ----
template <int CTRL>
__device__ __forceinline__ float dpp_mov(float x) {
  return __int_as_float(
      __builtin_amdgcn_update_dpp(0, __float_as_int(x), CTRL, 0xF, 0xF, false));
}

// 16-lane (DPP-row) inclusive sum; lane 15 of each 16-lane row holds the total.
__device__ __forceinline__ float reduce16(float v) {
  v += dpp_mov<0x111>(v);  // row_shr:1
  v += dpp_mov<0x112>(v);  // row_shr:2
  v += dpp_mov<0x114>(v);  // row_shr:4
  v += dpp_mov<0x118>(v);  // row_shr:8
  return v;
}

// ============================================================================
// Kernel 1: one WAVE per (b,n) tile; 4 waves/block share one b (and its 32KB
// q LDS stage).  Lane split: r = lane>>4 picks key rows, c = lane&15 covers a
// 64-float h-chunk (float4 per lane).
// Register-pressure discipline (hard-won):
//   R2: __launch_bounds__(256,4) => 64-VGPR cap => acc spill (4.2GB scratch)
//   R3: no bound => compiler fully unrolled gp x ch, pipelined ~all k-loads,
//       VGPR=256 + 2KB/thread scratch (2.1GB fetch, 0.5GB write)
//   Fix: unroll 1 on both streaming loops (manual depth-1 prefetch is the
//   ONLY in-flight state) + (256,2) => 128-VGPR ceiling >> ~90 live floats.
// ============================================================================
__global__ __launch_bounds__(256, 2) void score_kernel(
    const float* __restrict__ q, const float* __restrict__ keys,
    float* __restrict__ scores) {
  __shared__ float qs[8192];  // [chunk][t][c] float4 = 32 KB, q for this b

  const int bid  = blockIdx.x;   // 0..1023
  const int b    = bid >> 6;
  const int wave = threadIdx.x >> 6;
  const int lane = threadIdx.x & 63;
  const int n    = ((bid & 63) << 2) | wave;

  // ---- stage q[b]: qs[((ch*16 + t)*16 + c)] (float4 units) ----
  {
    const int tid = threadIdx.x;
#pragma unroll
    for (int k = 0; k < 8; ++k) {
      const int flat = tid + (k << 8);       // float4 index, 0..2047
      const int c  = flat & 15;
      const int t  = (flat >> 4) & 15;
      const int ch = flat >> 8;
      const float4 v =
          *(const float4*)(q + ((size_t)t * B_ + b) * H_ + ch * 64 + c * 4);
      *(float4*)(qs + (size_t)flat * 4) = v;
    }
  }
  __syncthreads();

  const int r = lane >> 4;
  const int c = lane & 15;
  const float* __restrict__ kb =
      keys + ((size_t)n * B_ + b) * (size_t)(L_ * H_);

  float smax[T_];
#pragma unroll
  for (int t = 0; t < T_; ++t) smax[t] = -3.4e38f;

#pragma unroll 1
  for (int gp = 0; gp < 8; ++gp) {  // rows jA = 8gp + r, jB = 8gp + 4 + r
    const float* pA = kb + (size_t)(8 * gp + r) * H_ + c * 4;
    const float* pB = pA + 4 * H_;

    float accA[T_], accB[T_];
#pragma unroll
    for (int t = 0; t < T_; ++t) accA[t] = accB[t] = 0.0f;

    float4 ka = *(const float4*)(pA);
    float4 kb4 = *(const float4*)(pB);

#pragma unroll 1
    for (int ch = 0; ch < 8; ++ch) {
      const int pf = (ch < 7 ? ch + 1 : 7) * 64;  // depth-1 prefetch (clamped)
      const float4 na = *(const float4*)(pA + pf);
      const float4 nb = *(const float4*)(pB + pf);

      const float* qv = qs + ((size_t)(ch << 8) << 2);  // qs[ch][0][0]
#pragma unroll
      for (int t = 0; t < T_; ++t) {
        const float4 q4 = *(const float4*)(qv + (((t << 4) + c) << 2));
        accA[t] = fmaf(ka.x, q4.x, accA[t]);
        accA[t] = fmaf(ka.y, q4.y, accA[t]);
        accA[t] = fmaf(ka.z, q4.z, accA[t]);
        accA[t] = fmaf(ka.w, q4.w, accA[t]);
        accB[t] = fmaf(kb4.x, q4.x, accB[t]);
        accB[t] = fmaf(kb4.y, q4.y, accB[t]);
        accB[t] = fmaf(kb4.z, q4.z, accB[t]);
        accB[t] = fmaf(kb4.w, q4.w, accB[t]);
      }
      ka = na;
      kb4 = nb;
    }

    // 16-lane reduce (4 row-groups in parallel); results valid at c == 15
#pragma unroll
    for (int t = 0; t < T_; ++t) {
      const float sA = reduce16(accA[t]);
      const float sB = reduce16(accB[t]);
      smax[t] = fmaxf(smax[t], fmaxf(sA, sB));
    }
  }

  // combine the 4 row-groups (lanes 15/31/47/63 hold per-group maxima)
#pragma unroll
  for (int t = 0; t < T_; ++t) {
    float v = smax[t];
    v = fmaxf(v, __shfl_xor(v, 16));
    v = fmaxf(v, __shfl_xor(v, 32));
    if (lane == 15)
      scores[(size_t)t * (B_ * N_) + b * N_ + n] = v;  // raw score, (T,B,N)
  }
}

// ============================================================================
// Kernel 2: one wave per (t,b) row.  In-place softmax over N=256, then top-8
// (value desc, index asc on ties).  Indices written as float values.
// ============================================================================
__global__ __launch_bounds__(256) void softmax_topk_kernel(
    float* __restrict__ att, float* __restrict__ out_idx) {
  const int row  = blockIdx.x * 4 + (threadIdx.x >> 6);  // t*B + b
  const int lane = threadIdx.x & 63;

  float* s = att + (size_t)row * N_;
  const float4 v4 = *(const float4*)(s + 4 * lane);
  const float v[4] = {v4.x, v4.y, v4.z, v4.w};

  float m = fmaxf(fmaxf(v[0], v[1]), fmaxf(v[2], v[3]));
#pragma unroll
  for (int d = 1; d < 64; d <<= 1) m = fmaxf(m, __shfl_xor(m, d));

  float p[4];
#pragma unroll
  for (int e = 0; e < 4; ++e) p[e] = expf(SCALE * (v[e] - m));

  float sum = p[0] + p[1] + p[2] + p[3];
#pragma unroll
  for (int d = 1; d < 64; d <<= 1) sum += __shfl_xor(sum, d);
  const float inv = 1.0f / sum;

  float a[4];
#pragma unroll
  for (int e = 0; e < 4; ++e) a[e] = p[e] * inv;

  *(float4*)(s + 4 * lane) = make_float4(a[0], a[1], a[2], a[3]);

  float w[4] = {a[0], a[1], a[2], a[3]};
  for (int kk = 0; kk < K_; ++kk) {
    float bv = w[0];
    int bn = 4 * lane;
#pragma unroll
    for (int e = 1; e < 4; ++e) {
      if (w[e] > bv) { bv = w[e]; bn = 4 * lane + e; }
    }
#pragma unroll
    for (int d = 1; d < 64; d <<= 1) {
      const float ov = __shfl_xor(bv, d);
      const int on = __shfl_xor(bn, d);
      if (ov > bv || (ov == bv && on < bn)) { bv = ov; bn = on; }
    }
    if (lane == 0) out_idx[kk * (T_ * B_) + row] = (float)bn;  // (k,T,B)
#pragma unroll
    for (int e = 0; e < 4; ++e)
      if (4 * lane + e == bn) w[e] = -1.0f;
  }
}

extern "C" void kernel_launch(void* const* d_in, const int* in_sizes, int n_in,
                              void* d_out, int out_size, void* d_ws,
                              size_t ws_size, hipStream_t stream) {
  const float* q    = (const float*)d_in[0];   // (T,1,B,H) fp32
  const float* keys = (const float*)d_in[1];   // (N,B,L*H) fp32
  float* out = (float*)d_out;
  float* att = out;                 // 65536 floats: raw scores -> attention
  float* idx = out + T_ * B_ * N_;  // 2048 floats: (k,T,B) indices as floats

  score_kernel<<<B_ * (N_ / 4), 256, 0, stream>>>(q, keys, att);
  softmax_topk_kernel<<<(T_ * B_) / 4, 256, 0, stream>>>(att, idx);
}

// Round 6
// 109.934 us; speedup vs baseline: 19.4538x; 1.0784x over previous
//
#include <hip/hip_runtime.h>
#include <hip/hip_bf16.h>
#include <math.h>

#define T_ 16
#define B_ 16
#define N_ 256
#define H_ 512
#define L_ 64
#define K_ 8
#define SCALE 0.04419417382415922f   // THETA / sqrt(512)

// ---- DPP helper ----
template <int CTRL>
__device__ __forceinline__ float dpp_mov(float x) {
  return __int_as_float(
      __builtin_amdgcn_update_dpp(0, __float_as_int(x), CTRL, 0xF, 0xF, false));
}

// 16-lane (DPP-row) inclusive sum; lane 15 of each 16-lane row holds the total.
__device__ __forceinline__ float reduce16(float v) {
  v += dpp_mov<0x111>(v);  // row_shr:1
  v += dpp_mov<0x112>(v);  // row_shr:2
  v += dpp_mov<0x114>(v);  // row_shr:4
  v += dpp_mov<0x118>(v);  // row_shr:8
  return v;
}

// ============================================================================
// Kernel 1: one WAVE per (b,n) tile; 4 waves/block share one b (32KB q LDS).
// Lane split: r = lane>>4 = row-group, c = lane&15 covers a 64-float h-chunk.
// R5 change vs R4: each group processes 4 key rows at once (j = 16gp+4i+r),
// so one broadcast ds_read_b128 of q feeds 16 FMAs (was 8) -> LDS-return pipe
// drops from ~96% to ~48% of HBM time (it was co-critical with HBM in R4).
// Running max lives in per-wave LDS psum (not regs) to stay under the cap.
// Register-pressure discipline (hard-won):
//   R2: (256,4) => 64-VGPR cap => acc spill (4.2GB scratch)
//   R3: no bound => full unroll, VGPR=256 + 2KB/thread scratch
//   Fix: unroll 1 on streaming loops + (256,2) => 128-VGPR ceiling; live
//   state = 64 acc + 32 k + ~20 misc ~= 118.
// ============================================================================
__global__ __launch_bounds__(256, 2) void score_kernel(
    const float* __restrict__ q, const float* __restrict__ keys,
    float* __restrict__ scores) {
  __shared__ float qs[8192];           // [chunk][t][c] float4 = 32 KB
  __shared__ float psum[4][4][4][16];  // [wave][gp][group][t] = 4 KB

  const int bid  = blockIdx.x;   // 0..1023
  const int b    = bid >> 6;
  const int wave = threadIdx.x >> 6;
  const int lane = threadIdx.x & 63;
  const int n    = ((bid & 63) << 2) | wave;

  // ---- stage q[b]: qs[((ch*16 + t)*16 + c)] (float4 units) ----
  {
    const int tid = threadIdx.x;
#pragma unroll
    for (int k = 0; k < 8; ++k) {
      const int flat = tid + (k << 8);       // float4 index, 0..2047
      const int c  = flat & 15;
      const int t  = (flat >> 4) & 15;
      const int ch = flat >> 8;
      const float4 v =
          *(const float4*)(q + ((size_t)t * B_ + b) * H_ + ch * 64 + c * 4);
      *(float4*)(qs + (size_t)flat * 4) = v;
    }
  }
  __syncthreads();

  const int r = lane >> 4;
  const int c = lane & 15;
  const float* __restrict__ kb =
      keys + ((size_t)n * B_ + b) * (size_t)(L_ * H_);

#pragma unroll 1
  for (int gp = 0; gp < 4; ++gp) {  // rows j = 16*gp + 4*i + r, i = 0..3
    const float* p0 = kb + (size_t)(16 * gp + r) * H_ + c * 4;
    const float* p1 = p0 + 4 * H_;
    const float* p2 = p0 + 8 * H_;
    const float* p3 = p0 + 12 * H_;

    float acc0[T_], acc1[T_], acc2[T_], acc3[T_];
#pragma unroll
    for (int t = 0; t < T_; ++t) acc0[t] = acc1[t] = acc2[t] = acc3[t] = 0.0f;

    float4 k0 = *(const float4*)(p0);
    float4 k1 = *(const float4*)(p1);
    float4 k2 = *(const float4*)(p2);
    float4 k3 = *(const float4*)(p3);

#pragma unroll 1
    for (int ch = 0; ch < 8; ++ch) {
      const int pf = (ch < 7 ? ch + 1 : 7) * 64;  // depth-1 prefetch (clamped)
      const float4 n0 = *(const float4*)(p0 + pf);
      const float4 n1 = *(const float4*)(p1 + pf);
      const float4 n2 = *(const float4*)(p2 + pf);
      const float4 n3 = *(const float4*)(p3 + pf);

      const float* qv = qs + (ch << 10);  // qs[ch][0][0]
#pragma unroll
      for (int t = 0; t < T_; ++t) {
        const float4 q4 = *(const float4*)(qv + (((t << 4) + c) << 2));
        acc0[t] = fmaf(k0.x, q4.x,
                  fmaf(k0.y, q4.y, fmaf(k0.z, q4.z, fmaf(k0.w, q4.w, acc0[t]))));
        acc1[t] = fmaf(k1.x, q4.x,
                  fmaf(k1.y, q4.y, fmaf(k1.z, q4.z, fmaf(k1.w, q4.w, acc1[t]))));
        acc2[t] = fmaf(k2.x, q4.x,
                  fmaf(k2.y, q4.y, fmaf(k2.z, q4.z, fmaf(k2.w, q4.w, acc2[t]))));
        acc3[t] = fmaf(k3.x, q4.x,
                  fmaf(k3.y, q4.y, fmaf(k3.z, q4.z, fmaf(k3.w, q4.w, acc3[t]))));
      }
      k0 = n0;
      k1 = n1;
      k2 = n2;
      k3 = n3;
    }

    // 16-lane reduce (4 rows per group, 4 groups in parallel); c==15 has sums
#pragma unroll
    for (int t = 0; t < T_; ++t) {
      const float s0 = reduce16(acc0[t]);
      const float s1 = reduce16(acc1[t]);
      const float s2 = reduce16(acc2[t]);
      const float s3 = reduce16(acc3[t]);
      if (c == 15)
        psum[wave][gp][r][t] = fmaxf(fmaxf(s0, s1), fmaxf(s2, s3));
    }
  }

  // epilogue: gather this wave's 16 per-(gp,group) maxima per t (same-wave
  // LDS dependence -> compiler-inserted lgkmcnt; no barrier needed)
  if (lane < 16) {
    float m = -3.4e38f;
#pragma unroll
    for (int gp = 0; gp < 4; ++gp)
#pragma unroll
      for (int g = 0; g < 4; ++g) m = fmaxf(m, psum[wave][gp][g][lane]);
    scores[(size_t)lane * (B_ * N_) + b * N_ + n] = m;  // raw score, (T,B,N)
  }
}

// ============================================================================
// Kernel 2: one wave per (t,b) row.  In-place softmax over N=256, then top-8
// (value desc, index asc on ties).  Indices written as float values.
// ============================================================================
__global__ __launch_bounds__(256) void softmax_topk_kernel(
    float* __restrict__ att, float* __restrict__ out_idx) {
  const int row  = blockIdx.x * 4 + (threadIdx.x >> 6);  // t*B + b
  const int lane = threadIdx.x & 63;

  float* s = att + (size_t)row * N_;
  const float4 v4 = *(const float4*)(s + 4 * lane);
  const float v[4] = {v4.x, v4.y, v4.z, v4.w};

  float m = fmaxf(fmaxf(v[0], v[1]), fmaxf(v[2], v[3]));
#pragma unroll
  for (int d = 1; d < 64; d <<= 1) m = fmaxf(m, __shfl_xor(m, d));

  float p[4];
#pragma unroll
  for (int e = 0; e < 4; ++e) p[e] = expf(SCALE * (v[e] - m));

  float sum = p[0] + p[1] + p[2] + p[3];
#pragma unroll
  for (int d = 1; d < 64; d <<= 1) sum += __shfl_xor(sum, d);
  const float inv = 1.0f / sum;

  float a[4];
#pragma unroll
  for (int e = 0; e < 4; ++e) a[e] = p[e] * inv;

  *(float4*)(s + 4 * lane) = make_float4(a[0], a[1], a[2], a[3]);

  float w[4] = {a[0], a[1], a[2], a[3]};
  for (int kk = 0; kk < K_; ++kk) {
    float bv = w[0];
    int bn = 4 * lane;
#pragma unroll
    for (int e = 1; e < 4; ++e) {
      if (w[e] > bv) { bv = w[e]; bn = 4 * lane + e; }
    }
#pragma unroll
    for (int d = 1; d < 64; d <<= 1) {
      const float ov = __shfl_xor(bv, d);
      const int on = __shfl_xor(bn, d);
      if (ov > bv || (ov == bv && on < bn)) { bv = ov; bn = on; }
    }
    if (lane == 0) out_idx[kk * (T_ * B_) + row] = (float)bn;  // (k,T,B)
#pragma unroll
    for (int e = 0; e < 4; ++e)
      if (4 * lane + e == bn) w[e] = -1.0f;
  }
}

extern "C" void kernel_launch(void* const* d_in, const int* in_sizes, int n_in,
                              void* d_out, int out_size, void* d_ws,
                              size_t ws_size, hipStream_t stream) {
  const float* q    = (const float*)d_in[0];   // (T,1,B,H) fp32
  const float* keys = (const float*)d_in[1];   // (N,B,L*H) fp32
  float* out = (float*)d_out;
  float* att = out;                 // 65536 floats: raw scores -> attention
  float* idx = out + T_ * B_ * N_;  // 2048 floats: (k,T,B) indices as floats

  score_kernel<<<B_ * (N_ / 4), 256, 0, stream>>>(q, keys, att);
  softmax_topk_kernel<<<(T_ * B_) / 4, 256, 0, stream>>>(att, idx);
}